// Round 1
// 265.593 us; speedup vs baseline: 1.1348x; 1.1348x over previous
//
#include <hip/hip_runtime.h>
#include <hip/hip_bf16.h>
#include <cstdint>

typedef __bf16 bf16_t;
typedef __bf16 bf16x4 __attribute__((ext_vector_type(4)));
typedef __bf16 bf16x8 __attribute__((ext_vector_type(8)));
typedef float floatx4 __attribute__((ext_vector_type(4)));

#define NB 4
#define NH 12
#define SEQ 2048
#define DM 768
#define LOG2E 1.44269504088896340736f

// async global->LDS, 16B per lane; LDS dest is wave-uniform base + lane*16
__device__ __forceinline__ void gload_lds16(const bf16_t* g, bf16_t* l) {
  auto gp = reinterpret_cast<const __attribute__((address_space(1))) uint32_t*>(
      reinterpret_cast<uintptr_t>(g));
  auto lp = reinterpret_cast<__attribute__((address_space(3))) uint32_t*>(
      reinterpret_cast<uintptr_t>(l));
  __builtin_amdgcn_global_load_lds(gp, lp, 16, 0, 0);
}

// ---------------------------------------------------------------- cvt f32->bf16
__global__ __launch_bounds__(256) void cvt_kernel(const float* __restrict__ in,
                                                  bf16_t* __restrict__ out) {
  int i = (blockIdx.x * 256 + threadIdx.x) * 4;
  float4 v = *(const float4*)(in + i);
  bf16x4 h;
  h[0] = (bf16_t)v.x; h[1] = (bf16_t)v.y; h[2] = (bf16_t)v.z; h[3] = (bf16_t)v.w;
  *(bf16x4*)(out + i) = h;
}

// ---------------------------------------------- transpose + cvt: in[K][N] -> out[N][K]
__global__ __launch_bounds__(256) void transpose_cvt_kernel(const float* __restrict__ in,
                                                            bf16_t* __restrict__ out,
                                                            int K, int N) {
  __shared__ float tile[32][33];
  int nb = blockIdx.x * 32, kb = blockIdx.y * 32;
  int tx = threadIdx.x & 31, ty = threadIdx.x >> 5;
#pragma unroll
  for (int r = ty; r < 32; r += 8)
    tile[r][tx] = in[(size_t)(kb + r) * N + nb + tx];
  __syncthreads();
#pragma unroll
  for (int r = ty; r < 32; r += 8)
    out[(size_t)(nb + r) * K + kb + tx] = (bf16_t)tile[tx][r];
}

// ---------------------------------------------------------------- QKV GEMM (m97 structure)
// A [8192][768] bf16, BT [2304][768] bf16. C = A@BT^T + bias, scattered into
// Q/K/V [B][H][S][64] bf16.  Q pre-scaled by hd^-0.5 * log2(e).
// 128x128 tile, 4 waves in 2x2, 64x64 out per wave, BK=32, global_load_lds(16B).
__global__ __launch_bounds__(256) void gemm_qkv_kernel(
    const bf16_t* __restrict__ A, const bf16_t* __restrict__ BT,
    const float* __restrict__ bias,
    bf16_t* __restrict__ Qo, bf16_t* __restrict__ Ko, bf16_t* __restrict__ Vo) {
  const int K = 768;
  __shared__ __align__(16) bf16_t As[128][32];
  __shared__ __align__(16) bf16_t Bs[128][32];
  const int m0 = blockIdx.x * 128, n0 = blockIdx.y * 128;
  const int tid = threadIdx.x;
  const int w = tid >> 6, lane = tid & 63, quad = lane >> 4, l16 = lane & 15;
  const int wm = w >> 1, wn = w & 1;
  // staging: wave w owns tile rows [w*32, w*32+32) for both As and Bs
  const int ldrow = w * 32;
  const int grow = lane >> 2;          // row within a 16-row chunk
  const int gcol = (lane & 3) * 8;     // bf16 column

  floatx4 acc[4][4];
#pragma unroll
  for (int mt = 0; mt < 4; mt++)
#pragma unroll
    for (int nt = 0; nt < 4; nt++) acc[mt][nt] = (floatx4)(0.f);

  const bf16_t* ga0 = A + (size_t)(m0 + ldrow) * K;
  const bf16_t* gb0 = BT + (size_t)(n0 + ldrow) * K;

  for (int k0 = 0; k0 < K; k0 += 32) {
    __syncthreads();  // previous tile fully consumed
    gload_lds16(ga0 + (size_t)grow * K + k0 + gcol,        &As[ldrow][0]);
    gload_lds16(ga0 + (size_t)(grow + 16) * K + k0 + gcol, &As[ldrow + 16][0]);
    gload_lds16(gb0 + (size_t)grow * K + k0 + gcol,        &Bs[ldrow][0]);
    gload_lds16(gb0 + (size_t)(grow + 16) * K + k0 + gcol, &Bs[ldrow + 16][0]);
    __syncthreads();  // vmcnt(0) drained by barrier -> tile ready
    bf16x8 af[4], bfr[4];
#pragma unroll
    for (int mt = 0; mt < 4; mt++)
      af[mt] = *(const bf16x8*)&As[wm * 64 + mt * 16 + l16][quad * 8];
#pragma unroll
    for (int nt = 0; nt < 4; nt++)
      bfr[nt] = *(const bf16x8*)&Bs[wn * 64 + nt * 16 + l16][quad * 8];
#pragma unroll
    for (int mt = 0; mt < 4; mt++)
#pragma unroll
      for (int nt = 0; nt < 4; nt++)
        acc[mt][nt] = __builtin_amdgcn_mfma_f32_16x16x32_bf16(af[mt], bfr[nt], acc[mt][nt], 0, 0, 0);
  }

  const int which = n0 / 768;  // 128 | 768 -> uniform per block
  const int rem0 = n0 % 768;
  bf16_t* dst = which == 0 ? Qo : (which == 1 ? Ko : Vo);
  const float qscale = which == 0 ? (0.125f * LOG2E) : 1.0f;
#pragma unroll
  for (int nt = 0; nt < 4; nt++) {
    const int cc = wn * 64 + nt * 16 + l16;
    const int rem = rem0 + cc;
    const int h = rem >> 6, hd = rem & 63;
    const float bv = bias[n0 + cc];
#pragma unroll
    for (int mt = 0; mt < 4; mt++)
#pragma unroll
      for (int r = 0; r < 4; r++) {
        const int gr = m0 + wm * 64 + mt * 16 + quad * 4 + r;
        const int bb = gr >> 11, s = gr & 2047;
        const float val = (acc[mt][nt][r] + bv) * qscale;
        dst[((size_t)((bb * NH + h) * SEQ + s)) * 64 + hd] = (bf16_t)val;
      }
  }
}

// ---------------------------------------------------------------- V transpose
// V [bh][S][64] -> Vt [bh][64][S]
__global__ __launch_bounds__(256) void vtrans_kernel(const bf16_t* __restrict__ V,
                                                     bf16_t* __restrict__ Vt) {
  __shared__ bf16_t tile[64][66];
  int bh = blockIdx.y, s0 = blockIdx.x * 64;
  int tid = threadIdx.x;
  int r = tid >> 4, c4 = (tid & 15) * 4;
  const bf16_t* src = V + (size_t)bh * SEQ * 64;
#pragma unroll
  for (int rr = r; rr < 64; rr += 16)
    *(bf16x4*)&tile[rr][c4] = *(const bf16x4*)&src[(size_t)(s0 + rr) * 64 + c4];
  __syncthreads();
  bf16_t* dst = Vt + (size_t)bh * 64 * SEQ;
#pragma unroll
  for (int hd = r; hd < 64; hd += 16) {
    bf16x4 o;
    o[0] = tile[c4 + 0][hd]; o[1] = tile[c4 + 1][hd];
    o[2] = tile[c4 + 2][hd]; o[3] = tile[c4 + 3][hd];
    *(bf16x4*)&dst[(size_t)hd * SEQ + s0 + c4] = o;
  }
}

// ---------------------------------------------------------------- flash attention, barrier-free
// (unchanged this round — control)
__global__ __launch_bounds__(256) void attn_kernel(
    const bf16_t* __restrict__ Q, const bf16_t* __restrict__ Kg,
    const bf16_t* __restrict__ Vt, bf16_t* __restrict__ Out) {
  __shared__ __align__(16) bf16_t Ps[4][16][68];
  const int tid = threadIdx.x;
  const int w = tid >> 6, lane = tid & 63;
  const int quad = lane >> 4, l16 = lane & 15;
  const int bh = blockIdx.x;
  const int b = bh / NH, h = bh % NH;
  const int qt = (int)(gridDim.y - 1) - (int)blockIdx.y;
  const int r0 = qt * 128 + w * 32;
  const bf16_t* Qp = Q + (size_t)bh * SEQ * 64;
  const bf16_t* Kp = Kg + (size_t)bh * SEQ * 64;
  const bf16_t* Vp = Vt + (size_t)bh * 64 * SEQ;

  bf16x8 qf[2][2];
#pragma unroll
  for (int rs = 0; rs < 2; rs++)
#pragma unroll
    for (int hh = 0; hh < 2; hh++)
      qf[rs][hh] = *(const bf16x8*)&Qp[(size_t)(r0 + rs * 16 + l16) * 64 + hh * 32 + quad * 8];

  float m_i[2][4], l_i[2][4];
  floatx4 acc[2][4];
#pragma unroll
  for (int rs = 0; rs < 2; rs++)
#pragma unroll
    for (int r = 0; r < 4; r++) { m_i[rs][r] = -1e30f; l_i[rs][r] = 0.f; }
#pragma unroll
  for (int rs = 0; rs < 2; rs++)
#pragma unroll
    for (int ot = 0; ot < 4; ot++) acc[rs][ot] = (floatx4)(0.f);

  const int nt = ((r0 + 31) >> 6) + 1;
  for (int kt = 0; kt < nt; kt++) {
    const int kbase = kt * 64;
    bf16x8 kf[4][2];
#pragma unroll
    for (int ct = 0; ct < 4; ct++)
#pragma unroll
      for (int hh = 0; hh < 2; hh++)
        kf[ct][hh] = *(const bf16x8*)&Kp[(size_t)(kbase + ct * 16 + l16) * 64 + hh * 32 + quad * 8];
    floatx4 s[2][4];
#pragma unroll
    for (int rs = 0; rs < 2; rs++)
#pragma unroll
      for (int ct = 0; ct < 4; ct++) {
        floatx4 z = (floatx4)(0.f);
        z = __builtin_amdgcn_mfma_f32_16x16x32_bf16(qf[rs][0], kf[ct][0], z, 0, 0, 0);
        z = __builtin_amdgcn_mfma_f32_16x16x32_bf16(qf[rs][1], kf[ct][1], z, 0, 0, 0);
        s[rs][ct] = z;
      }
    if (kt == nt - 1) {
#pragma unroll
      for (int rs = 0; rs < 2; rs++)
#pragma unroll
        for (int ct = 0; ct < 4; ct++) {
          int key = kbase + ct * 16 + l16;
#pragma unroll
          for (int r = 0; r < 4; r++) {
            int row = r0 + rs * 16 + quad * 4 + r;
            if (key > row) s[rs][ct][r] = -1e30f;
          }
        }
    }
    bf16x8 vf[4][2];
#pragma unroll
    for (int ot = 0; ot < 4; ot++)
#pragma unroll
      for (int kh = 0; kh < 2; kh++)
        vf[ot][kh] = *(const bf16x8*)&Vp[(size_t)(ot * 16 + l16) * SEQ + kbase + kh * 32 + quad * 8];
#pragma unroll
    for (int rs = 0; rs < 2; rs++) {
      float alpha_r[4];
      asm volatile("s_waitcnt lgkmcnt(0)" ::: "memory");
#pragma unroll
      for (int r = 0; r < 4; r++) {
        float mt = fmaxf(fmaxf(s[rs][0][r], s[rs][1][r]), fmaxf(s[rs][2][r], s[rs][3][r]));
#pragma unroll
        for (int off = 8; off >= 1; off >>= 1)
          mt = fmaxf(mt, __shfl_xor(mt, off, 16));
        float mnew = fmaxf(m_i[rs][r], mt);
        float al = __builtin_amdgcn_exp2f(m_i[rs][r] - mnew);
        m_i[rs][r] = mnew;
        float p0 = __builtin_amdgcn_exp2f(s[rs][0][r] - mnew);
        float p1 = __builtin_amdgcn_exp2f(s[rs][1][r] - mnew);
        float p2 = __builtin_amdgcn_exp2f(s[rs][2][r] - mnew);
        float p3 = __builtin_amdgcn_exp2f(s[rs][3][r] - mnew);
        Ps[w][quad * 4 + r][0 * 16 + l16] = (bf16_t)p0;
        Ps[w][quad * 4 + r][1 * 16 + l16] = (bf16_t)p1;
        Ps[w][quad * 4 + r][2 * 16 + l16] = (bf16_t)p2;
        Ps[w][quad * 4 + r][3 * 16 + l16] = (bf16_t)p3;
        float rsum = (p0 + p1) + (p2 + p3);
#pragma unroll
        for (int off = 8; off >= 1; off >>= 1)
          rsum += __shfl_xor(rsum, off, 16);
        l_i[rs][r] = l_i[rs][r] * al + rsum;
        alpha_r[r] = al;
      }
#pragma unroll
      for (int ot = 0; ot < 4; ot++)
#pragma unroll
        for (int r = 0; r < 4; r++) acc[rs][ot][r] *= alpha_r[r];
      asm volatile("s_waitcnt lgkmcnt(0)" ::: "memory");
      bf16x8 pf0 = *(const bf16x8*)&Ps[w][l16][0 * 32 + quad * 8];
      bf16x8 pf1 = *(const bf16x8*)&Ps[w][l16][1 * 32 + quad * 8];
#pragma unroll
      for (int ot = 0; ot < 4; ot++) {
        acc[rs][ot] = __builtin_amdgcn_mfma_f32_16x16x32_bf16(pf0, vf[ot][0], acc[rs][ot], 0, 0, 0);
        acc[rs][ot] = __builtin_amdgcn_mfma_f32_16x16x32_bf16(pf1, vf[ot][1], acc[rs][ot], 0, 0, 0);
      }
    }
  }
#pragma unroll
  for (int rs = 0; rs < 2; rs++)
#pragma unroll
    for (int ot = 0; ot < 4; ot++)
#pragma unroll
      for (int r = 0; r < 4; r++) {
        int row = r0 + rs * 16 + quad * 4 + r;
        float o = acc[rs][ot][r] / l_i[rs][r];
        Out[((size_t)(b * SEQ + row)) * DM + h * 64 + ot * 16 + l16] = (bf16_t)o;
      }
}

// ---------------------------------------------------------------- out-proj GEMM (m97 structure)
__global__ __launch_bounds__(256) void gemm_proj_kernel(
    const bf16_t* __restrict__ A, const bf16_t* __restrict__ BT,
    const float* __restrict__ bias, float* __restrict__ out) {
  const int K = 768;
  __shared__ __align__(16) bf16_t As[128][32];
  __shared__ __align__(16) bf16_t Bs[128][32];
  const int m0 = blockIdx.x * 128, n0 = blockIdx.y * 128;
  const int tid = threadIdx.x;
  const int w = tid >> 6, lane = tid & 63, quad = lane >> 4, l16 = lane & 15;
  const int wm = w >> 1, wn = w & 1;
  const int ldrow = w * 32;
  const int grow = lane >> 2;
  const int gcol = (lane & 3) * 8;

  floatx4 acc[4][4];
#pragma unroll
  for (int mt = 0; mt < 4; mt++)
#pragma unroll
    for (int nt = 0; nt < 4; nt++) acc[mt][nt] = (floatx4)(0.f);

  const bf16_t* ga0 = A + (size_t)(m0 + ldrow) * K;
  const bf16_t* gb0 = BT + (size_t)(n0 + ldrow) * K;

  for (int k0 = 0; k0 < K; k0 += 32) {
    __syncthreads();
    gload_lds16(ga0 + (size_t)grow * K + k0 + gcol,        &As[ldrow][0]);
    gload_lds16(ga0 + (size_t)(grow + 16) * K + k0 + gcol, &As[ldrow + 16][0]);
    gload_lds16(gb0 + (size_t)grow * K + k0 + gcol,        &Bs[ldrow][0]);
    gload_lds16(gb0 + (size_t)(grow + 16) * K + k0 + gcol, &Bs[ldrow + 16][0]);
    __syncthreads();
    bf16x8 af[4], bfr[4];
#pragma unroll
    for (int mt = 0; mt < 4; mt++)
      af[mt] = *(const bf16x8*)&As[wm * 64 + mt * 16 + l16][quad * 8];
#pragma unroll
    for (int nt = 0; nt < 4; nt++)
      bfr[nt] = *(const bf16x8*)&Bs[wn * 64 + nt * 16 + l16][quad * 8];
#pragma unroll
    for (int mt = 0; mt < 4; mt++)
#pragma unroll
      for (int nt = 0; nt < 4; nt++)
        acc[mt][nt] = __builtin_amdgcn_mfma_f32_16x16x32_bf16(af[mt], bfr[nt], acc[mt][nt], 0, 0, 0);
  }

#pragma unroll
  for (int nt = 0; nt < 4; nt++) {
    const int gc = n0 + wn * 64 + nt * 16 + l16;
    const float bv = bias[gc];
#pragma unroll
    for (int mt = 0; mt < 4; mt++)
#pragma unroll
      for (int r = 0; r < 4; r++) {
        const int gr = m0 + wm * 64 + mt * 16 + quad * 4 + r;
        out[(size_t)gr * 768 + gc] = acc[mt][nt][r] + bv;
      }
  }
}

// ---------------------------------------------------------------- launch
extern "C" void kernel_launch(void* const* d_in, const int* in_sizes, int n_in,
                              void* d_out, int out_size, void* d_ws, size_t ws_size,
                              hipStream_t stream) {
  const float* x      = (const float*)d_in[0];
  const float* w_qkv  = (const float*)d_in[1];
  const float* b_qkv  = (const float*)d_in[2];
  const float* w_proj = (const float*)d_in[3];
  const float* b_proj = (const float*)d_in[4];
  float* out = (float*)d_out;
  char* ws = (char*)d_ws;

  // workspace layout (all 16B-aligned), total 67,633,152 B
  bf16_t* xb     = (bf16_t*)(ws + 0);         // 8192*768  bf16 (dead after gemm_qkv)
  bf16_t* wqkvT  = (bf16_t*)(ws + 12582912);  // 2304*768  bf16
  bf16_t* wprojT = (bf16_t*)(ws + 16121856);  //  768*768  bf16
  bf16_t* q      = (bf16_t*)(ws + 17301504);  // [4][12][2048][64] bf16
  bf16_t* k      = (bf16_t*)(ws + 29884416);
  bf16_t* v      = (bf16_t*)(ws + 42467328);
  bf16_t* ao     = (bf16_t*)(ws + 55050240);  // [8192][768] bf16
  bf16_t* vt     = xb;                        // aliases xb: [4][12][64][2048] bf16

  cvt_kernel<<<6144, 256, 0, stream>>>(x, xb);
  transpose_cvt_kernel<<<dim3(72, 24), 256, 0, stream>>>(w_qkv, wqkvT, 768, 2304);
  transpose_cvt_kernel<<<dim3(24, 24), 256, 0, stream>>>(w_proj, wprojT, 768, 768);
  gemm_qkv_kernel<<<dim3(64, 18), 256, 0, stream>>>(xb, wqkvT, b_qkv, q, k, v);
  vtrans_kernel<<<dim3(32, 48), 256, 0, stream>>>(v, vt);
  attn_kernel<<<dim3(48, 16), 256, 0, stream>>>(q, k, vt, ao);
  gemm_proj_kernel<<<dim3(64, 6), 256, 0, stream>>>(ao, wprojT, b_proj, out);
}